// Round 9
// baseline (519.867 us; speedup 1.0000x reference)
//
#include <hip/hip_runtime.h>
#include <hip/hip_bf16.h>

typedef __bf16  bf16x8 __attribute__((ext_vector_type(8)));
typedef float   f32x4  __attribute__((ext_vector_type(4)));
typedef short   s16x8  __attribute__((ext_vector_type(8)));

typedef const __attribute__((address_space(1))) void g_void;
typedef __attribute__((address_space(3))) void l_void;

__device__ __forceinline__ short f2b(float x) {
    __hip_bfloat16 h = __float2bfloat16(x);
    return __builtin_bit_cast(short, h);
}

// pack two floats to bf16 pair in one int (lo | hi<<16)
__device__ __forceinline__ int pk2(float lo, float hi) {
    return (int)(unsigned short)f2b(lo) | ((int)f2b(hi) << 16);
}

// fast GELU: tanh form via hardware exp2. gelu(v) = v*t/(t+1),
// t = exp2(K1*(v + 0.044715 v^3)), K1 = 2*log2(e)*0.7978845608.
__device__ __forceinline__ float fast_gelu(float v) {
    const float a = fminf(2.3022082f * (v + 0.044715f * v * v * v), 126.0f);
    const float t = exp2f(a);
    return v * t / (t + 1.0f);
}

__device__ __forceinline__ f32x4 mfma16(s16x8 a, s16x8 b, f32x4 c) {
    return __builtin_amdgcn_mfma_f32_16x16x32_bf16(
        __builtin_bit_cast(bf16x8, a), __builtin_bit_cast(bf16x8, b), c, 0, 0, 0);
}

// ---------------- transpose + fp32 -> bf16 :  src [R,C] f32 -> dst [C,R] bf16
__global__ __launch_bounds__(256) void transpose_bf16(
    const float* __restrict__ src, short* __restrict__ dst, int R, int C) {
    __shared__ float tile[32][33];
    src += (size_t)blockIdx.z * R * C;
    dst += (size_t)blockIdx.z * R * C;
    const int c0 = blockIdx.x * 32, r0 = blockIdx.y * 32;
    const int tx = threadIdx.x & 31, ty = threadIdx.x >> 5;
#pragma unroll
    for (int i = 0; i < 32; i += 8)
        tile[ty + i][tx] = src[(size_t)(r0 + ty + i) * C + c0 + tx];
    __syncthreads();
#pragma unroll
    for (int i = 0; i < 32; i += 8)
        dst[(size_t)(c0 + ty + i) * R + r0 + tx] = f2b(tile[tx][ty + i]);
}

// ---------------- concat q/k/v bias into [3072] f32
__global__ __launch_bounds__(256) void concat_bias(
    const float* __restrict__ bq, const float* __restrict__ bk,
    const float* __restrict__ bv, float* __restrict__ o) {
    int i = blockIdx.x * 256 + threadIdx.x;
    if (i < 1024)      o[i] = bq[i];
    else if (i < 2048) o[i] = bk[i - 1024];
    else if (i < 3072) o[i] = bv[i - 2048];
}

// ---------------- LayerNorm (D=1024) f32 in -> bf16 out. 1 block/row, 256 thr
__global__ __launch_bounds__(256) void ln_bf16(
    const float* __restrict__ x, const float* __restrict__ gamma,
    const float* __restrict__ beta, short* __restrict__ out) {
    __shared__ float red[8];
    const int row = blockIdx.x, tid = threadIdx.x;
    const float4 v = *(const float4*)(x + (size_t)row * 1024 + tid * 4);
    float s = v.x + v.y + v.z + v.w;
    float q = v.x * v.x + v.y * v.y + v.z * v.z + v.w * v.w;
#pragma unroll
    for (int off = 32; off > 0; off >>= 1) {
        s += __shfl_xor(s, off);
        q += __shfl_xor(q, off);
    }
    if ((tid & 63) == 0) { red[(tid >> 6) * 2] = s; red[(tid >> 6) * 2 + 1] = q; }
    __syncthreads();
    s = red[0] + red[2] + red[4] + red[6];
    q = red[1] + red[3] + red[5] + red[7];
    const float mu = s * (1.0f / 1024.0f);
    const float var = q * (1.0f / 1024.0f) - mu * mu;
    const float rs = rsqrtf(var + 1e-5f);
    const float4 g  = *(const float4*)(gamma + tid * 4);
    const float4 bt = *(const float4*)(beta + tid * 4);
    short4 o;
    o.x = f2b((v.x - mu) * rs * g.x + bt.x);
    o.y = f2b((v.y - mu) * rs * g.y + bt.y);
    o.z = f2b((v.z - mu) * rs * g.z + bt.z);
    o.w = f2b((v.w - mu) * rs * g.w + bt.w);
    *(short4*)(out + (size_t)row * 1024 + tid * 4) = o;
}

// ---------------- bf16 MFMA GEMM: C[M,N] = A[M,K] * Bt[N,K]^T (+ epilogue)
// 128x128 tile, BK=64 as two 32-K panels, 512 threads (8 waves).
// Swizzle v2: each XCD owns an N-band (B-slice <= ~1 MB -> resident in its
// 4 MB L2 across the whole M sweep); s sweeps n-within-band fast, m slow.
// g = 8s + xcd keeps all 8 XCDs on the SAME m-tile concurrently -> each
// A-tile is HBM-fetched once and L3-served to the rest. Requires gx%8==0.
// MODE 0: QKV scatter: Q (pre-scaled by 1/8*log2e), K -> [2][B,H,S,HD];
//         V -> vt [B,H,HD,S]
// MODE 1: out f32 = acc + bias[col] + resid[row*N+col]
// MODE 2: out bf16 = fast_gelu(acc + bias[col])
template <int MODE>
__global__ __launch_bounds__(512) void gemm_bf16(
    const short* __restrict__ A, const short* __restrict__ Bt,
    const float* __restrict__ bias, const float* __restrict__ resid,
    float* __restrict__ outf, short* __restrict__ outb, short* __restrict__ vt,
    int M, int N, int K) {
    __shared__ __align__(16) short As[2 * 128 * 32];
    __shared__ __align__(16) short Bs[2 * 128 * 32];

    const int tid = threadIdx.x;
    const int wave = tid >> 6, lane = tid & 63;
    const int l16 = lane & 15, quad = lane >> 4;
    const int wm = wave & 3, wn = wave >> 2;   // 4 row-strips x 2 col-strips
    // --- XCD swizzle v2 (requires gridDim.x % 8 == 0) ---
    const int gx = gridDim.x;
    const int g = blockIdx.y * gx + blockIdx.x;
    const int xcd = g & 7, s = g >> 3;
    const int nband = gx >> 3;                 // n-tiles per XCD
    const int sm = s / nband;                  // slow: m sweep
    const int sn = s - sm * nband;             // fast: n within band
    const int m0 = sm * 128;
    const int n0 = (xcd * nband + sn) * 128;
    const int lrow = lane >> 2;        // 0..15
    const int lcol = (lane & 3) * 8;   // 16B chunk within a 32-elem panel row

    f32x4 acc[2][4] = {};

    for (int kk = 0; kk < K; kk += 64) {
#pragma unroll
        for (int p = 0; p < 2; ++p) {        // 32-K panel
            const int r = wave * 16 + lrow;  // 8 waves x 16 rows = 128
            const short* ga = A + (size_t)(m0 + r) * K + kk + p * 32 + lcol;
            short* la = &As[p * 4096 + wave * 512];
            __builtin_amdgcn_global_load_lds((g_void*)ga, (l_void*)la, 16, 0, 0);
            const short* gb = Bt + (size_t)(n0 + r) * K + kk + p * 32 + lcol;
            short* lb = &Bs[p * 4096 + wave * 512];
            __builtin_amdgcn_global_load_lds((g_void*)gb, (l_void*)lb, 16, 0, 0);
        }
        __syncthreads();
#pragma unroll
        for (int p = 0; p < 2; ++p) {
            s16x8 a[2], b[4];
#pragma unroll
            for (int t = 0; t < 2; ++t)
                a[t] = *(const s16x8*)&As[p * 4096 + (wm * 32 + t * 16 + l16) * 32 + quad * 8];
#pragma unroll
            for (int t = 0; t < 4; ++t)
                b[t] = *(const s16x8*)&Bs[p * 4096 + (wn * 64 + t * 16 + l16) * 32 + quad * 8];
#pragma unroll
            for (int mt = 0; mt < 2; ++mt)
#pragma unroll
                for (int nt = 0; nt < 4; ++nt)
                    acc[mt][nt] = mfma16(a[mt], b[nt], acc[mt][nt]);
        }
        __syncthreads();
    }

#pragma unroll
    for (int mt = 0; mt < 2; ++mt) {
#pragma unroll
        for (int nt = 0; nt < 4; ++nt) {
            const int row = m0 + wm * 32 + mt * 16 + quad * 4;   // + r
            const int col = n0 + wn * 64 + nt * 16 + l16;
            const float bc = bias[col];
            float v[4];
#pragma unroll
            for (int r = 0; r < 4; ++r) v[r] = acc[mt][nt][r] + bc;

            if (MODE == 0) {
                const int sel = col >> 10, within = col & 1023;
                const int h = within >> 6, hd = within & 63;
                const size_t bidx = (size_t)row >> 11, sp = row & 2047;
                if (sel == 0) {
                    // fold softmax scale (1/sqrt(64) * log2e) into Q
#pragma unroll
                    for (int r = 0; r < 4; ++r) v[r] *= 0.18033688011112042f;
                }
                if (sel < 2) {
#pragma unroll
                    for (int r = 0; r < 4; ++r)
                        outb[(size_t)sel * (8192ull * 1024) +
                             ((bidx * 16 + h) * 2048 + sp + r) * 64 + hd] = f2b(v[r]);
                } else {
                    short4 o4;
                    o4.x = f2b(v[0]); o4.y = f2b(v[1]);
                    o4.z = f2b(v[2]); o4.w = f2b(v[3]);
                    *(short4*)&vt[((bidx * 16 + h) * 64 + hd) * 2048 + sp] = o4;
                }
            } else if (MODE == 1) {
#pragma unroll
                for (int r = 0; r < 4; ++r) {
                    const size_t rr = (size_t)(row + r);
                    outf[rr * N + col] = v[r] + resid[rr * N + col];
                }
            } else {
#pragma unroll
                for (int r = 0; r < 4; ++r)
                    outb[(size_t)(row + r) * N + col] = f2b(fast_gelu(v[r]));
            }
        }
    }
}

// ---------------- causal flash attention v3: S^T formulation, no-max softmax,
// double-buffered K/V tiles (ONE barrier per iteration), 512 blocks x 4
// balanced passes {g, 15-g, 16+g, 31-g} (66 iters for every block).
// Q (pre-scaled),K bf16 [B,H,S,HD]; Vt bf16 [B,H,HD,S]; O bf16 [B,S,H*HD].
__global__ __launch_bounds__(256) void attn_kernel(
    const short* __restrict__ Q, const short* __restrict__ K,
    const short* __restrict__ Vt, short* __restrict__ O) {
    const int bid = blockIdx.x;
    const int gq = bid & 7;
    const int h  = (bid >> 3) & 15;
    const int b  = bid >> 7;
    const int tid = threadIdx.x, wave = tid >> 6, lane = tid & 63;
    const int l16 = lane & 15, quad = lane >> 4;

    __shared__ __align__(16) short Ks[2][64 * 72];
    __shared__ __align__(16) short Vts[2][64 * 72];
    __shared__ __align__(16) short Ps[4][16 * 72];

    const size_t bh = ((size_t)b * 16 + h) * (2048ull * 64);
    const int srow = tid >> 2;
    const int sseg = (tid & 3) * 16;

    const int qts[4] = {gq, 15 - gq, 16 + gq, 31 - gq};

    for (int pass = 0; pass < 4; ++pass) {
        const int qt = qts[pass];
        const int q0 = qt * 64;
        const int q_lane = q0 + wave * 16 + l16;

        const short* qrow = Q + bh + (size_t)q_lane * 64;
        s16x8 bq0 = *(const s16x8*)(qrow + quad * 8);
        s16x8 bq1 = *(const s16x8*)(qrow + 32 + quad * 8);

        f32x4 oacc[4] = {};
        float lsum = 0.0f;

        // prologue: load j=0 tile
        s16x8 k0, k1, v0, v1;
        {
            const short* kg = K + bh + (size_t)srow * 64 + sseg;
            k0 = *(const s16x8*)kg;
            k1 = *(const s16x8*)(kg + 8);
            const short* vg = Vt + bh + (size_t)srow * 2048 + sseg;
            v0 = *(const s16x8*)vg;
            v1 = *(const s16x8*)(vg + 8);
        }

        for (int j = 0; j <= qt; ++j) {
            const int buf = j & 1;
            // write this tile into its buffer, then ONE barrier.
            // safety: reads of buf from iter j-2 precede barrier j-1.
            *(s16x8*)&Ks[buf][srow * 72 + sseg]      = k0;
            *(s16x8*)&Ks[buf][srow * 72 + sseg + 8]  = k1;
            *(s16x8*)&Vts[buf][srow * 72 + sseg]     = v0;
            *(s16x8*)&Vts[buf][srow * 72 + sseg + 8] = v1;
            __syncthreads();

            // prefetch next tile while computing this one
            if (j < qt) {
                const short* kg = K + bh + (size_t)((j + 1) * 64 + srow) * 64 + sseg;
                k0 = *(const s16x8*)kg;
                k1 = *(const s16x8*)(kg + 8);
                const short* vg = Vt + bh + (size_t)srow * 2048 + (j + 1) * 64 + sseg;
                v0 = *(const s16x8*)vg;
                v1 = *(const s16x8*)(vg + 8);
            }

            // S^T = K·Qᵀ: st[s][r] = S[q=l16][t = j*64 + s*16 + quad*4 + r]
            f32x4 st[4];
#pragma unroll
            for (int s = 0; s < 4; ++s) {
                s16x8 ak0 = *(const s16x8*)&Ks[buf][(s * 16 + l16) * 72 + quad * 8];
                s16x8 ak1 = *(const s16x8*)&Ks[buf][(s * 16 + l16) * 72 + 32 + quad * 8];
                f32x4 c = {};
                c = mfma16(ak0, bq0, c);
                c = mfma16(ak1, bq1, c);
                st[s] = c;
            }
            // causal mask (diagonal tile only); scale already folded into Q
            if (j == qt) {
#pragma unroll
                for (int s = 0; s < 4; ++s)
#pragma unroll
                    for (int r = 0; r < 4; ++r) {
                        const int t = j * 64 + s * 16 + quad * 4 + r;
                        if (t > q_lane) st[s][r] = -3000.0f;
                    }
            }
            // p = exp2(s)  (no max subtraction), row sum, pack P to LDS
            float rs = 0.0f;
#pragma unroll
            for (int s = 0; s < 4; ++s) {
#pragma unroll
                for (int r = 0; r < 4; ++r) {
                    st[s][r] = exp2f(st[s][r]);
                    rs += st[s][r];
                }
                int2 pw;
                pw.x = pk2(st[s][0], st[s][1]);
                pw.y = pk2(st[s][2], st[s][3]);
                *(int2*)&Ps[wave][l16 * 72 + s * 16 + quad * 4] = pw;
            }
            rs += __shfl_xor(rs, 16);
            rs += __shfl_xor(rs, 32);
            lsum += rs;

            asm volatile("s_waitcnt lgkmcnt(0)" ::: "memory");
            s16x8 ap0 = *(const s16x8*)&Ps[wave][l16 * 72 + quad * 8];
            s16x8 ap1 = *(const s16x8*)&Ps[wave][l16 * 72 + 32 + quad * 8];

            // O += P V
#pragma unroll
            for (int nt = 0; nt < 4; ++nt) {
                s16x8 bv0 = *(const s16x8*)&Vts[buf][(nt * 16 + l16) * 72 + quad * 8];
                s16x8 bv1 = *(const s16x8*)&Vts[buf][(nt * 16 + l16) * 72 + 32 + quad * 8];
                oacc[nt] = mfma16(ap0, bv0, oacc[nt]);
                oacc[nt] = mfma16(ap1, bv1, oacc[nt]);
            }
        }
        __syncthreads();   // all reads done before next pass restages buf0

        // epilogue: O[b, s, h*64+hd] bf16; lsum lives in l16 domain -> shfl
        float inv[4];
#pragma unroll
        for (int r = 0; r < 4; ++r)
            inv[r] = 1.0f / __shfl(lsum, quad * 4 + r, 64);
#pragma unroll
        for (int nt = 0; nt < 4; ++nt)
#pragma unroll
            for (int r = 0; r < 4; ++r) {
                const int row = q0 + wave * 16 + quad * 4 + r;
                O[((size_t)b * 2048 + row) * 1024 + h * 64 + nt * 16 + l16] =
                    f2b(oacc[nt][r] * inv[r]);
            }
    }
}

extern "C" void kernel_launch(void* const* d_in, const int* in_sizes, int n_in,
                              void* d_out, int out_size, void* d_ws, size_t ws_size,
                              hipStream_t stream) {
    const float* x     = (const float*)d_in[0];
    const float* Wq    = (const float*)d_in[1];
    const float* Wk    = (const float*)d_in[2];
    const float* Wv    = (const float*)d_in[3];
    const float* bq    = (const float*)d_in[4];
    const float* bk    = (const float*)d_in[5];
    const float* bv    = (const float*)d_in[6];
    const float* Wo    = (const float*)d_in[7];
    const float* bo    = (const float*)d_in[8];
    const float* W1    = (const float*)d_in[9];
    const float* b1    = (const float*)d_in[10];
    const float* W2    = (const float*)d_in[11];
    const float* b2    = (const float*)d_in[12];
    const float* gamma = (const float*)d_in[13];
    const float* beta  = (const float*)d_in[14];
    float* out = (float*)d_out;

    char* ws = (char*)d_ws;
    size_t off = 0;
    auto alloc = [&](size_t bytes) -> char* {
        char* p = ws + off;
        off += (bytes + 255) & ~(size_t)255;
        return p;
    };
    short* h1    = (short*)alloc(8192ull * 1024 * 2);
    short* btqkv = (short*)alloc(3072ull * 1024 * 2);
    short* btwo  = (short*)alloc(1024ull * 1024 * 2);
    short* btw1  = (short*)alloc(4096ull * 1024 * 2);
    short* btw2  = (short*)alloc(1024ull * 4096 * 2);
    float* bqkv  = (float*)alloc(3072ull * 4);
    short* qkv   = (short*)alloc(2ull * 8192 * 1024 * 2);   // Q,K only
    short* vt    = (short*)alloc(8192ull * 1024 * 2);       // V pre-transposed
    short* aout  = (short*)alloc(8192ull * 1024 * 2);
    float* x2    = (float*)alloc(8192ull * 1024 * 4);
    short* h2    = (short*)alloc(8192ull * 1024 * 2);
    short* m1    = (short*)alloc(8192ull * 4096 * 2);

    // weight prep
    transpose_bf16<<<dim3(2, 32, 16), 256, 0, stream>>>(Wq, btqkv, 1024, 64);
    transpose_bf16<<<dim3(2, 32, 16), 256, 0, stream>>>(Wk, btqkv + 1024ull * 1024, 1024, 64);
    transpose_bf16<<<dim3(2, 32, 16), 256, 0, stream>>>(Wv, btqkv + 2ull * 1024 * 1024, 1024, 64);
    transpose_bf16<<<dim3(32, 32, 1), 256, 0, stream>>>(Wo, btwo, 1024, 1024);
    transpose_bf16<<<dim3(128, 32, 1), 256, 0, stream>>>(W1, btw1, 1024, 4096);
    transpose_bf16<<<dim3(32, 128, 1), 256, 0, stream>>>(W2, btw2, 4096, 1024);
    concat_bias<<<12, 256, 0, stream>>>(bq, bk, bv, bqkv);

    // LN1
    ln_bf16<<<8192, 256, 0, stream>>>(x, gamma, beta, h1);
    // QKV projection (V written directly transposed into vt; Q pre-scaled)
    gemm_bf16<0><<<dim3(24, 64), 512, 0, stream>>>(
        h1, btqkv, bqkv, nullptr, nullptr, qkv, vt, 8192, 3072, 1024);
    // attention
    attn_kernel<<<512, 256, 0, stream>>>(
        qkv, qkv + 8192ull * 1024, vt, aout);
    // Wo + residual -> x2 (f32)
    gemm_bf16<1><<<dim3(8, 64), 512, 0, stream>>>(
        aout, btwo, bo, x, x2, nullptr, nullptr, 8192, 1024, 1024);
    // LN2
    ln_bf16<<<8192, 256, 0, stream>>>(x2, gamma, beta, h2);
    // MLP1 + GELU (fast tanh-form, exp2-based)
    gemm_bf16<2><<<dim3(32, 64), 512, 0, stream>>>(
        h2, btw1, b1, nullptr, nullptr, m1, nullptr, 8192, 4096, 1024);
    // MLP2 + residual -> out (f32)
    gemm_bf16<1><<<dim3(8, 64), 512, 0, stream>>>(
        m1, btw2, b2, x2, out, nullptr, nullptr, 8192, 1024, 4096);
}

// Round 10
// 511.477 us; speedup vs baseline: 1.0164x; 1.0164x over previous
//
#include <hip/hip_runtime.h>
#include <hip/hip_bf16.h>

typedef __bf16  bf16x8 __attribute__((ext_vector_type(8)));
typedef float   f32x4  __attribute__((ext_vector_type(4)));
typedef short   s16x8  __attribute__((ext_vector_type(8)));

typedef const __attribute__((address_space(1))) void g_void;
typedef __attribute__((address_space(3))) void l_void;

__device__ __forceinline__ short f2b(float x) {
    __hip_bfloat16 h = __float2bfloat16(x);
    return __builtin_bit_cast(short, h);
}

// pack two floats to bf16 pair in one int (lo | hi<<16)
__device__ __forceinline__ int pk2(float lo, float hi) {
    return (int)(unsigned short)f2b(lo) | ((int)f2b(hi) << 16);
}

// fast GELU: tanh form via hardware exp2. gelu(v) = v*t/(t+1),
// t = exp2(K1*(v + 0.044715 v^3)), K1 = 2*log2(e)*0.7978845608.
__device__ __forceinline__ float fast_gelu(float v) {
    const float a = fminf(2.3022082f * (v + 0.044715f * v * v * v), 126.0f);
    const float t = exp2f(a);
    return v * t / (t + 1.0f);
}

__device__ __forceinline__ f32x4 mfma16(s16x8 a, s16x8 b, f32x4 c) {
    return __builtin_amdgcn_mfma_f32_16x16x32_bf16(
        __builtin_bit_cast(bf16x8, a), __builtin_bit_cast(bf16x8, b), c, 0, 0, 0);
}

// ---------------- transpose + fp32 -> bf16 :  src [R,C] f32 -> dst [C,R] bf16
__global__ __launch_bounds__(256) void transpose_bf16(
    const float* __restrict__ src, short* __restrict__ dst, int R, int C) {
    __shared__ float tile[32][33];
    src += (size_t)blockIdx.z * R * C;
    dst += (size_t)blockIdx.z * R * C;
    const int c0 = blockIdx.x * 32, r0 = blockIdx.y * 32;
    const int tx = threadIdx.x & 31, ty = threadIdx.x >> 5;
#pragma unroll
    for (int i = 0; i < 32; i += 8)
        tile[ty + i][tx] = src[(size_t)(r0 + ty + i) * C + c0 + tx];
    __syncthreads();
#pragma unroll
    for (int i = 0; i < 32; i += 8)
        dst[(size_t)(c0 + ty + i) * R + r0 + tx] = f2b(tile[tx][ty + i]);
}

// ---------------- concat q/k/v bias into [3072] f32
__global__ __launch_bounds__(256) void concat_bias(
    const float* __restrict__ bq, const float* __restrict__ bk,
    const float* __restrict__ bv, float* __restrict__ o) {
    int i = blockIdx.x * 256 + threadIdx.x;
    if (i < 1024)      o[i] = bq[i];
    else if (i < 2048) o[i] = bk[i - 1024];
    else if (i < 3072) o[i] = bv[i - 2048];
}

// ---------------- LayerNorm (D=1024) f32 in -> bf16 out. 1 block/row, 256 thr
__global__ __launch_bounds__(256) void ln_bf16(
    const float* __restrict__ x, const float* __restrict__ gamma,
    const float* __restrict__ beta, short* __restrict__ out) {
    __shared__ float red[8];
    const int row = blockIdx.x, tid = threadIdx.x;
    const float4 v = *(const float4*)(x + (size_t)row * 1024 + tid * 4);
    float s = v.x + v.y + v.z + v.w;
    float q = v.x * v.x + v.y * v.y + v.z * v.z + v.w * v.w;
#pragma unroll
    for (int off = 32; off > 0; off >>= 1) {
        s += __shfl_xor(s, off);
        q += __shfl_xor(q, off);
    }
    if ((tid & 63) == 0) { red[(tid >> 6) * 2] = s; red[(tid >> 6) * 2 + 1] = q; }
    __syncthreads();
    s = red[0] + red[2] + red[4] + red[6];
    q = red[1] + red[3] + red[5] + red[7];
    const float mu = s * (1.0f / 1024.0f);
    const float var = q * (1.0f / 1024.0f) - mu * mu;
    const float rs = rsqrtf(var + 1e-5f);
    const float4 g  = *(const float4*)(gamma + tid * 4);
    const float4 bt = *(const float4*)(beta + tid * 4);
    short4 o;
    o.x = f2b((v.x - mu) * rs * g.x + bt.x);
    o.y = f2b((v.y - mu) * rs * g.y + bt.y);
    o.z = f2b((v.z - mu) * rs * g.z + bt.z);
    o.w = f2b((v.w - mu) * rs * g.w + bt.w);
    *(short4*)(out + (size_t)row * 1024 + tid * 4) = o;
}

// ---------------- bf16 MFMA GEMM: C[M,N] = A[M,K] * Bt[N,K]^T (+ epilogue)
// 128x128 tile, BK=64 as two 32-K panels, 512 threads (8 waves).
// SWZ 0 (N-band, for wide-N): each XCD owns an N-band whose B-slice stays
//   L2-resident; all XCDs sweep the same m-tile concurrently (A via L3).
// SWZ 1 (M-band, for narrow-N/long-K, e.g. MLP2): each XCD owns a contiguous
//   M-band; co-resident blocks share one A-tile per L2 fill (measured best
//   for MLP2 in R8: FETCH 283->137 MB).
// MODE 0: QKV scatter: Q (pre-scaled by 1/8*log2e), K -> [2][B,H,S,HD];
//         V -> vt [B,H,HD,S]
// MODE 1: out f32 = acc + bias[col] + resid[row*N+col]
// MODE 2: out bf16 = fast_gelu(acc + bias[col])
template <int MODE, int SWZ>
__global__ __launch_bounds__(512) void gemm_bf16(
    const short* __restrict__ A, const short* __restrict__ Bt,
    const float* __restrict__ bias, const float* __restrict__ resid,
    float* __restrict__ outf, short* __restrict__ outb, short* __restrict__ vt,
    int M, int N, int K) {
    __shared__ __align__(16) short As[2 * 128 * 32];
    __shared__ __align__(16) short Bs[2 * 128 * 32];

    const int tid = threadIdx.x;
    const int wave = tid >> 6, lane = tid & 63;
    const int l16 = lane & 15, quad = lane >> 4;
    const int wm = wave & 3, wn = wave >> 2;   // 4 row-strips x 2 col-strips
    const int gx = gridDim.x;
    const int g = blockIdx.y * gx + blockIdx.x;
    const int xcd = g & 7, s = g >> 3;
    int m0, n0;
    if (SWZ == 0) {                            // N-band (requires gx % 8 == 0)
        const int nband = gx >> 3;
        const int sm = s / nband;
        const int sn = s - sm * nband;
        m0 = sm * 128;
        n0 = (xcd * nband + sn) * 128;
    } else {                                   // M-band (requires gy % 8 == 0)
        const int mband = gridDim.y >> 3;
        const int sm = s / gx;
        m0 = (xcd * mband + sm) * 128;
        n0 = (s - sm * gx) * 128;
    }
    const int lrow = lane >> 2;        // 0..15
    const int lcol = (lane & 3) * 8;   // 16B chunk within a 32-elem panel row

    f32x4 acc[2][4] = {};

    for (int kk = 0; kk < K; kk += 64) {
#pragma unroll
        for (int p = 0; p < 2; ++p) {        // 32-K panel
            const int r = wave * 16 + lrow;  // 8 waves x 16 rows = 128
            const short* ga = A + (size_t)(m0 + r) * K + kk + p * 32 + lcol;
            short* la = &As[p * 4096 + wave * 512];
            __builtin_amdgcn_global_load_lds((g_void*)ga, (l_void*)la, 16, 0, 0);
            const short* gb = Bt + (size_t)(n0 + r) * K + kk + p * 32 + lcol;
            short* lb = &Bs[p * 4096 + wave * 512];
            __builtin_amdgcn_global_load_lds((g_void*)gb, (l_void*)lb, 16, 0, 0);
        }
        __syncthreads();
#pragma unroll
        for (int p = 0; p < 2; ++p) {
            s16x8 a[2], b[4];
#pragma unroll
            for (int t = 0; t < 2; ++t)
                a[t] = *(const s16x8*)&As[p * 4096 + (wm * 32 + t * 16 + l16) * 32 + quad * 8];
#pragma unroll
            for (int t = 0; t < 4; ++t)
                b[t] = *(const s16x8*)&Bs[p * 4096 + (wn * 64 + t * 16 + l16) * 32 + quad * 8];
#pragma unroll
            for (int mt = 0; mt < 2; ++mt)
#pragma unroll
                for (int nt = 0; nt < 4; ++nt)
                    acc[mt][nt] = mfma16(a[mt], b[nt], acc[mt][nt]);
        }
        __syncthreads();
    }

#pragma unroll
    for (int mt = 0; mt < 2; ++mt) {
#pragma unroll
        for (int nt = 0; nt < 4; ++nt) {
            const int row = m0 + wm * 32 + mt * 16 + quad * 4;   // + r
            const int col = n0 + wn * 64 + nt * 16 + l16;
            const float bc = bias[col];
            float v[4];
#pragma unroll
            for (int r = 0; r < 4; ++r) v[r] = acc[mt][nt][r] + bc;

            if (MODE == 0) {
                const int sel = col >> 10, within = col & 1023;
                const int h = within >> 6, hd = within & 63;
                const size_t bidx = (size_t)row >> 11, sp = row & 2047;
                if (sel == 0) {
                    // fold softmax scale (1/sqrt(64) * log2e) into Q
#pragma unroll
                    for (int r = 0; r < 4; ++r) v[r] *= 0.18033688011112042f;
                }
                if (sel < 2) {
#pragma unroll
                    for (int r = 0; r < 4; ++r)
                        outb[(size_t)sel * (8192ull * 1024) +
                             ((bidx * 16 + h) * 2048 + sp + r) * 64 + hd] = f2b(v[r]);
                } else {
                    short4 o4;
                    o4.x = f2b(v[0]); o4.y = f2b(v[1]);
                    o4.z = f2b(v[2]); o4.w = f2b(v[3]);
                    *(short4*)&vt[((bidx * 16 + h) * 64 + hd) * 2048 + sp] = o4;
                }
            } else if (MODE == 1) {
#pragma unroll
                for (int r = 0; r < 4; ++r) {
                    const size_t rr = (size_t)(row + r);
                    outf[rr * N + col] = v[r] + resid[rr * N + col];
                }
            } else {
#pragma unroll
                for (int r = 0; r < 4; ++r)
                    outb[(size_t)(row + r) * N + col] = f2b(fast_gelu(v[r]));
            }
        }
    }
}

// ---------------- causal flash attention v4: S^T formulation, no-max softmax,
// double-buffered K/V (one barrier/iter), XCD-affinity block mapping:
// all 8 sub-blocks of one (b,h) share bid%8 -> same XCD, so its K/V stream
// (0.5 MB) is L2-resident; per-XCD working set 8 bh x 0.5 MB = 4 MB = L2.
// 512 blocks x 4 balanced passes {g, 15-g, 16+g, 31-g} (66 iters/block).
__global__ __launch_bounds__(256) void attn_kernel(
    const short* __restrict__ Q, const short* __restrict__ K,
    const short* __restrict__ Vt, short* __restrict__ O) {
    const int bid = blockIdx.x;
    const int xcd = bid & 7;
    const int sub = (bid >> 3) & 7;    // gq
    const int grp = bid >> 6;          // 0..7
    const int bh  = grp * 8 + xcd;     // bh % 8 == xcd
    const int h = bh & 15, b = bh >> 4;
    const int gq = sub;
    const int tid = threadIdx.x, wave = tid >> 6, lane = tid & 63;
    const int l16 = lane & 15, quad = lane >> 4;

    __shared__ __align__(16) short Ks[2][64 * 72];
    __shared__ __align__(16) short Vts[2][64 * 72];
    __shared__ __align__(16) short Ps[4][16 * 72];

    const size_t bhoff = (size_t)bh * (2048ull * 64);
    const int srow = tid >> 2;
    const int sseg = (tid & 3) * 16;

    const int qts[4] = {gq, 15 - gq, 16 + gq, 31 - gq};

    for (int pass = 0; pass < 4; ++pass) {
        const int qt = qts[pass];
        const int q0 = qt * 64;
        const int q_lane = q0 + wave * 16 + l16;

        const short* qrow = Q + bhoff + (size_t)q_lane * 64;
        s16x8 bq0 = *(const s16x8*)(qrow + quad * 8);
        s16x8 bq1 = *(const s16x8*)(qrow + 32 + quad * 8);

        f32x4 oacc[4] = {};
        float lsum = 0.0f;

        // prologue: load j=0 tile
        s16x8 k0, k1, v0, v1;
        {
            const short* kg = K + bhoff + (size_t)srow * 64 + sseg;
            k0 = *(const s16x8*)kg;
            k1 = *(const s16x8*)(kg + 8);
            const short* vg = Vt + bhoff + (size_t)srow * 2048 + sseg;
            v0 = *(const s16x8*)vg;
            v1 = *(const s16x8*)(vg + 8);
        }

        for (int j = 0; j <= qt; ++j) {
            const int buf = j & 1;
            // write this tile into its buffer, then ONE barrier.
            // safety: reads of buf from iter j-2 precede barrier j-1.
            *(s16x8*)&Ks[buf][srow * 72 + sseg]      = k0;
            *(s16x8*)&Ks[buf][srow * 72 + sseg + 8]  = k1;
            *(s16x8*)&Vts[buf][srow * 72 + sseg]     = v0;
            *(s16x8*)&Vts[buf][srow * 72 + sseg + 8] = v1;
            __syncthreads();

            // prefetch next tile while computing this one
            if (j < qt) {
                const short* kg = K + bhoff + (size_t)((j + 1) * 64 + srow) * 64 + sseg;
                k0 = *(const s16x8*)kg;
                k1 = *(const s16x8*)(kg + 8);
                const short* vg = Vt + bhoff + (size_t)srow * 2048 + (j + 1) * 64 + sseg;
                v0 = *(const s16x8*)vg;
                v1 = *(const s16x8*)(vg + 8);
            }

            // S^T = K·Qᵀ: st[s][r] = S[q=l16][t = j*64 + s*16 + quad*4 + r]
            f32x4 st[4];
#pragma unroll
            for (int s = 0; s < 4; ++s) {
                s16x8 ak0 = *(const s16x8*)&Ks[buf][(s * 16 + l16) * 72 + quad * 8];
                s16x8 ak1 = *(const s16x8*)&Ks[buf][(s * 16 + l16) * 72 + 32 + quad * 8];
                f32x4 c = {};
                c = mfma16(ak0, bq0, c);
                c = mfma16(ak1, bq1, c);
                st[s] = c;
            }
            // causal mask (diagonal tile only); scale already folded into Q
            if (j == qt) {
#pragma unroll
                for (int s = 0; s < 4; ++s)
#pragma unroll
                    for (int r = 0; r < 4; ++r) {
                        const int t = j * 64 + s * 16 + quad * 4 + r;
                        if (t > q_lane) st[s][r] = -3000.0f;
                    }
            }
            // p = exp2(s)  (no max subtraction), row sum, pack P to LDS
            float rs = 0.0f;
#pragma unroll
            for (int s = 0; s < 4; ++s) {
#pragma unroll
                for (int r = 0; r < 4; ++r) {
                    st[s][r] = exp2f(st[s][r]);
                    rs += st[s][r];
                }
                int2 pw;
                pw.x = pk2(st[s][0], st[s][1]);
                pw.y = pk2(st[s][2], st[s][3]);
                *(int2*)&Ps[wave][l16 * 72 + s * 16 + quad * 4] = pw;
            }
            rs += __shfl_xor(rs, 16);
            rs += __shfl_xor(rs, 32);
            lsum += rs;

            asm volatile("s_waitcnt lgkmcnt(0)" ::: "memory");
            s16x8 ap0 = *(const s16x8*)&Ps[wave][l16 * 72 + quad * 8];
            s16x8 ap1 = *(const s16x8*)&Ps[wave][l16 * 72 + 32 + quad * 8];

            // O += P V
#pragma unroll
            for (int nt = 0; nt < 4; ++nt) {
                s16x8 bv0 = *(const s16x8*)&Vts[buf][(nt * 16 + l16) * 72 + quad * 8];
                s16x8 bv1 = *(const s16x8*)&Vts[buf][(nt * 16 + l16) * 72 + 32 + quad * 8];
                oacc[nt] = mfma16(ap0, bv0, oacc[nt]);
                oacc[nt] = mfma16(ap1, bv1, oacc[nt]);
            }
        }
        __syncthreads();   // all reads done before next pass restages buf0

        // epilogue: O[b, s, h*64+hd] bf16; lsum lives in l16 domain -> shfl
        float inv[4];
#pragma unroll
        for (int r = 0; r < 4; ++r)
            inv[r] = 1.0f / __shfl(lsum, quad * 4 + r, 64);
#pragma unroll
        for (int nt = 0; nt < 4; ++nt)
#pragma unroll
            for (int r = 0; r < 4; ++r) {
                const int row = q0 + wave * 16 + quad * 4 + r;
                O[((size_t)b * 2048 + row) * 1024 + h * 64 + nt * 16 + l16] =
                    f2b(oacc[nt][r] * inv[r]);
            }
    }
}

extern "C" void kernel_launch(void* const* d_in, const int* in_sizes, int n_in,
                              void* d_out, int out_size, void* d_ws, size_t ws_size,
                              hipStream_t stream) {
    const float* x     = (const float*)d_in[0];
    const float* Wq    = (const float*)d_in[1];
    const float* Wk    = (const float*)d_in[2];
    const float* Wv    = (const float*)d_in[3];
    const float* bq    = (const float*)d_in[4];
    const float* bk    = (const float*)d_in[5];
    const float* bv    = (const float*)d_in[6];
    const float* Wo    = (const float*)d_in[7];
    const float* bo    = (const float*)d_in[8];
    const float* W1    = (const float*)d_in[9];
    const float* b1    = (const float*)d_in[10];
    const float* W2    = (const float*)d_in[11];
    const float* b2    = (const float*)d_in[12];
    const float* gamma = (const float*)d_in[13];
    const float* beta  = (const float*)d_in[14];
    float* out = (float*)d_out;

    char* ws = (char*)d_ws;
    size_t off = 0;
    auto alloc = [&](size_t bytes) -> char* {
        char* p = ws + off;
        off += (bytes + 255) & ~(size_t)255;
        return p;
    };
    short* h1    = (short*)alloc(8192ull * 1024 * 2);
    short* btqkv = (short*)alloc(3072ull * 1024 * 2);
    short* btwo  = (short*)alloc(1024ull * 1024 * 2);
    short* btw1  = (short*)alloc(4096ull * 1024 * 2);
    short* btw2  = (short*)alloc(1024ull * 4096 * 2);
    float* bqkv  = (float*)alloc(3072ull * 4);
    short* qkv   = (short*)alloc(2ull * 8192 * 1024 * 2);   // Q,K only
    short* vt    = (short*)alloc(8192ull * 1024 * 2);       // V pre-transposed
    short* aout  = (short*)alloc(8192ull * 1024 * 2);
    float* x2    = (float*)alloc(8192ull * 1024 * 4);
    short* h2    = (short*)alloc(8192ull * 1024 * 2);
    short* m1    = (short*)alloc(8192ull * 4096 * 2);

    // weight prep
    transpose_bf16<<<dim3(2, 32, 16), 256, 0, stream>>>(Wq, btqkv, 1024, 64);
    transpose_bf16<<<dim3(2, 32, 16), 256, 0, stream>>>(Wk, btqkv + 1024ull * 1024, 1024, 64);
    transpose_bf16<<<dim3(2, 32, 16), 256, 0, stream>>>(Wv, btqkv + 2ull * 1024 * 1024, 1024, 64);
    transpose_bf16<<<dim3(32, 32, 1), 256, 0, stream>>>(Wo, btwo, 1024, 1024);
    transpose_bf16<<<dim3(128, 32, 1), 256, 0, stream>>>(W1, btw1, 1024, 4096);
    transpose_bf16<<<dim3(32, 128, 1), 256, 0, stream>>>(W2, btw2, 4096, 1024);
    concat_bias<<<12, 256, 0, stream>>>(bq, bk, bv, bqkv);

    // LN1
    ln_bf16<<<8192, 256, 0, stream>>>(x, gamma, beta, h1);
    // QKV projection (V written directly transposed into vt; Q pre-scaled)
    gemm_bf16<0, 0><<<dim3(24, 64), 512, 0, stream>>>(
        h1, btqkv, bqkv, nullptr, nullptr, qkv, vt, 8192, 3072, 1024);
    // attention (XCD-affinity mapping)
    attn_kernel<<<512, 256, 0, stream>>>(
        qkv, qkv + 8192ull * 1024, vt, aout);
    // Wo + residual -> x2 (f32)
    gemm_bf16<1, 0><<<dim3(8, 64), 512, 0, stream>>>(
        aout, btwo, bo, x, x2, nullptr, nullptr, 8192, 1024, 1024);
    // LN2
    ln_bf16<<<8192, 256, 0, stream>>>(x2, gamma, beta, h2);
    // MLP1 + GELU (fast tanh-form, exp2-based)
    gemm_bf16<2, 0><<<dim3(32, 64), 512, 0, stream>>>(
        h2, btw1, b1, nullptr, nullptr, m1, nullptr, 8192, 4096, 1024);
    // MLP2 + residual -> out (f32), M-band swizzle (R8-measured best)
    gemm_bf16<1, 1><<<dim3(8, 64), 512, 0, stream>>>(
        m1, btw2, b2, x2, out, nullptr, nullptr, 8192, 1024, 4096);
}